// Round 1
// baseline (1326.660 us; speedup 1.0000x reference)
//
#include <hip/hip_runtime.h>
#include <math.h>

#define F_IN 128
#define HID 64
#define NHEAD 4
#define NLAYER 3

// ---------------- CSR build ----------------
__global__ __launch_bounds__(256) void zero_ints(int* __restrict__ a, int* __restrict__ b, int n) {
  int i = blockIdx.x * 256 + threadIdx.x;
  if (i < n) { a[i] = 0; b[i] = 0; }
}
__global__ __launch_bounds__(256) void zero_f(float* __restrict__ p, int n) {
  int i = blockIdx.x * 256 + threadIdx.x;
  if (i < n) p[i] = 0.f;
}
__global__ __launch_bounds__(256) void hist_k(const int* __restrict__ dst, int* __restrict__ cnt, int e) {
  int i = blockIdx.x * 256 + threadIdx.x;
  if (i < e) atomicAdd(&cnt[dst[i]], 1);
}
__global__ __launch_bounds__(1024) void scan_block_k(const int* __restrict__ cnt, int* __restrict__ excl,
                                                     int* __restrict__ bsum, int n) {
  __shared__ int tmp[1024];
  int t = threadIdx.x;
  int i = blockIdx.x * 1024 + t;
  int v = (i < n) ? cnt[i] : 0;
  tmp[t] = v;
  __syncthreads();
  for (int off = 1; off < 1024; off <<= 1) {
    int add = (t >= off) ? tmp[t - off] : 0;
    __syncthreads();
    tmp[t] += add;
    __syncthreads();
  }
  if (i < n) excl[i] = tmp[t] - v;
  if (t == 1023) bsum[blockIdx.x] = tmp[1023];
}
__global__ void scan_bsum_k(int* __restrict__ bsum, int nb) {
  if (threadIdx.x == 0 && blockIdx.x == 0) {
    int run = 0;
    for (int b = 0; b < nb; b++) { int x = bsum[b]; bsum[b] = run; run += x; }
  }
}
__global__ __launch_bounds__(256) void finalize_rowptr_k(const int* __restrict__ excl, const int* __restrict__ bsum,
                                                         int* __restrict__ rowp, int n, int e) {
  int i = blockIdx.x * 256 + threadIdx.x;
  if (i < n) rowp[i] = excl[i] + bsum[i >> 10];
  if (i == 0) rowp[n] = e;
}
__global__ __launch_bounds__(256) void scatter_k(const int* __restrict__ src, const int* __restrict__ dst,
                                                 const int* __restrict__ rowp, int* __restrict__ cur,
                                                 int* __restrict__ srt, int e) {
  int i = blockIdx.x * 256 + threadIdx.x;
  if (i < e) {
    int d = dst[i];
    int pos = rowp[d] + atomicAdd(&cur[d], 1);
    srt[pos] = src[i];
  }
}

// ---------------- GEMM: out[n,OUTW] = A[n,K] @ W[K,OUTW] + bias ----------------
// Weight column held in VGPRs per thread; activation row read via wave-uniform
// address -> s_load broadcast -> inner loop is pure v_fma.
template <int OUTW, int K>
__global__ __launch_bounds__(256) void gemm_k(const float* __restrict__ A, const float* __restrict__ W,
                                              const float* __restrict__ bias, float* __restrict__ out,
                                              int n, int rows_per_block) {
  constexpr int RG = 256 / OUTW;  // row-groups (waves covering different rows)
  int c = threadIdx.x % OUTW;
  int rg = __builtin_amdgcn_readfirstlane((int)(threadIdx.x / OUTW));
  float w[K];
#pragma unroll
  for (int kk = 0; kk < K; kk++) w[kk] = W[kk * OUTW + c];
  float b = bias[c];
  int r0 = blockIdx.x * rows_per_block;
  int r1 = r0 + rows_per_block;
  if (r1 > n) r1 = n;
  for (int r = r0 + rg; r < r1; r += RG) {
    const float* __restrict__ a = A + (size_t)r * K;
    float acc = b;
#pragma unroll
    for (int kk = 0; kk < K; kk++) acc = fmaf(a[kk], w[kk], acc);
    out[(size_t)r * OUTW + c] = acc;
  }
}

// ---------------- fused attention + head-mean + skip + relu ----------------
// One wave per node. Lane layout: head = lane>>4, c-chunk = (lane&15)*4.
// Each gathered K/V row is one coalesced 1KB wave load (64 lanes x float4).
__global__ __launch_bounds__(256) void attn_k(const float* __restrict__ q, const float* __restrict__ kx,
                                              const float* __restrict__ vx, const float* __restrict__ sk,
                                              const int* __restrict__ rowp, const int* __restrict__ srt,
                                              float* __restrict__ hn, int n) {
  int wv = __builtin_amdgcn_readfirstlane((int)(threadIdx.x >> 6));
  int node = blockIdx.x * 4 + wv;
  if (node >= n) return;
  int lane = threadIdx.x & 63;
  int hd = lane >> 4;
  int c0 = (lane & 15) << 2;
  const float4 q4 = *(const float4*)(q + (size_t)node * 256 + hd * 64 + c0);
  float qx = q4.x * 0.125f, qy = q4.y * 0.125f, qz = q4.z * 0.125f, qw = q4.w * 0.125f;  // scale=1/sqrt(64)
  int rs = rowp[node], re = rowp[node + 1];
  float m = -INFINITY, d = 0.f;
  float ax = 0.f, ay = 0.f, az = 0.f, aw = 0.f;
  for (int i = rs; i < re; i++) {
    int sidx = srt[i];  // wave-uniform -> s_load
    const float4 k4 = *(const float4*)(kx + (size_t)sidx * 256 + hd * 64 + c0);
    float t = qx * k4.x + qy * k4.y + qz * k4.z + qw * k4.w;
    t += __shfl_xor(t, 1);
    t += __shfl_xor(t, 2);
    t += __shfl_xor(t, 4);
    t += __shfl_xor(t, 8);  // per-16-lane (per-head) dot reduce
    float mn = fmaxf(m, t);
    float co = __expf(m - mn);  // m=-inf first iter -> co=0
    float p = __expf(t - mn);
    d = d * co + p;
    const float4 v4 = *(const float4*)(vx + (size_t)sidx * 256 + hd * 64 + c0);
    ax = ax * co + p * v4.x;
    ay = ay * co + p * v4.y;
    az = az * co + p * v4.z;
    aw = aw * co + p * v4.w;
    m = mn;
  }
  float rx, ry, rz, rw;
  if (d > 0.f) {
    float inv = 1.f / d;
    rx = ax * inv; ry = ay * inv; rz = az * inv; rw = aw * inv;
  } else {
    rx = ry = rz = rw = 0.f;  // nodes with no incoming edges
  }
  // sum over the 4 head groups (lanes differing in bits 16/32)
  rx += __shfl_xor(rx, 16); rx += __shfl_xor(rx, 32);
  ry += __shfl_xor(ry, 16); ry += __shfl_xor(ry, 32);
  rz += __shfl_xor(rz, 16); rz += __shfl_xor(rz, 32);
  rw += __shfl_xor(rw, 16); rw += __shfl_xor(rw, 32);
  if (hd == 0) {
    const float4 s4 = *(const float4*)(sk + (size_t)node * 64 + c0);
    float4 o;
    o.x = fmaxf(rx * 0.25f + s4.x, 0.f);
    o.y = fmaxf(ry * 0.25f + s4.y, 0.f);
    o.z = fmaxf(rz * 0.25f + s4.z, 0.f);
    o.w = fmaxf(rw * 0.25f + s4.w, 0.f);
    *(float4*)(hn + (size_t)node * 64 + c0) = o;
  }
}

// ---------------- global add pool ----------------
__global__ __launch_bounds__(256) void pool_k(const float* __restrict__ h, const int* __restrict__ batch,
                                              float* __restrict__ out, int n) {
  int i = blockIdx.x * 256 + threadIdx.x;
  if (i < n * 64) {
    int node = i >> 6, c = i & 63;
    atomicAdd(&out[batch[node] * 64 + c], h[i]);
  }
}

extern "C" void kernel_launch(void* const* d_in, const int* in_sizes, int n_in,
                              void* d_out, int out_size, void* d_ws, size_t ws_size,
                              hipStream_t stream) {
  const float* x  = (const float*)d_in[0];
  const int* ei   = (const int*)d_in[1];
  const int* batch = (const int*)d_in[2];
  const float* w0 = (const float*)d_in[3];
  const float* b0 = (const float*)d_in[4];
  const float* Wq = (const float*)d_in[5];
  const float* bq = (const float*)d_in[6];
  const float* Wk = (const float*)d_in[7];
  const float* bk = (const float*)d_in[8];
  const float* Wv = (const float*)d_in[9];
  const float* bv = (const float*)d_in[10];
  const float* Ws = (const float*)d_in[11];
  const float* bs = (const float*)d_in[12];
  int N = in_sizes[0] / F_IN;
  int E = in_sizes[1] / 2;
  const int* esrc = ei;
  const int* edst = ei + E;

  // workspace layout (fp32 + int), ~182 MB total
  float* f = (float*)d_ws;
  float* h0 = f;
  float* h1 = h0 + (size_t)N * HID;
  float* q  = h1 + (size_t)N * HID;
  float* k  = q + (size_t)N * HID * NHEAD;
  float* v  = k + (size_t)N * HID * NHEAD;
  float* sb = v + (size_t)N * HID * NHEAD;
  int* cnt  = (int*)(sb + (size_t)N * HID);
  int* cur  = cnt + N;
  int* excl = cur + N;
  int* rowp = excl + N;
  int* bsum = rowp + N + 1;
  int* srt  = bsum + 64;

  int nbN = (N + 255) / 256;
  int nbE = (E + 255) / 256;
  int sbBlocks = (N + 1023) / 1024;

  // CSR by dst (rebuilt every call; deterministic up to FP-order noise)
  zero_ints<<<nbN, 256, 0, stream>>>(cnt, cur, N);
  hist_k<<<nbE, 256, 0, stream>>>(edst, cnt, E);
  scan_block_k<<<sbBlocks, 1024, 0, stream>>>(cnt, excl, bsum, N);
  scan_bsum_k<<<1, 64, 0, stream>>>(bsum, sbBlocks);
  finalize_rowptr_k<<<nbN, 256, 0, stream>>>(excl, bsum, rowp, N, E);
  scatter_k<<<nbE, 256, 0, stream>>>(esrc, edst, rowp, cur, srt, E);

  const int RPB = 32;
  int gBlocks = (N + RPB - 1) / RPB;

  // h0 = x @ lin0_w + lin0_b
  gemm_k<HID, F_IN><<<gBlocks, 256, 0, stream>>>(x, w0, b0, h0, N, RPB);

  float* hc = h0;
  float* hx = h1;
  for (int l = 0; l < NLAYER; l++) {
    const size_t wOff = (size_t)l * HID * (NHEAD * HID);
    gemm_k<256, HID><<<gBlocks, 256, 0, stream>>>(hc, Wq + wOff, bq + l * 256, q, N, RPB);
    gemm_k<256, HID><<<gBlocks, 256, 0, stream>>>(hc, Wk + wOff, bk + l * 256, k, N, RPB);
    gemm_k<256, HID><<<gBlocks, 256, 0, stream>>>(hc, Wv + wOff, bv + l * 256, v, N, RPB);
    gemm_k<HID, HID><<<gBlocks, 256, 0, stream>>>(hc, Ws + (size_t)l * HID * HID, bs + l * HID, sb, N, RPB);
    attn_k<<<(N + 3) / 4, 256, 0, stream>>>(q, k, v, sb, rowp, srt, hx, N);
    float* t = hc; hc = hx; hx = t;
  }

  zero_f<<<(out_size + 255) / 256, 256, 0, stream>>>((float*)d_out, out_size);
  pool_k<<<((N * 64) + 255) / 256, 256, 0, stream>>>(hc, batch, (float*)d_out, N);
}

// Round 2
// 1157.789 us; speedup vs baseline: 1.1459x; 1.1459x over previous
//
#include <hip/hip_runtime.h>
#include <math.h>

#define F_IN 128
#define HID 64
#define NHEAD 4
#define NLAYER 3

// ---------------- CSR build ----------------
__global__ __launch_bounds__(256) void zero_ints(int* __restrict__ a, int* __restrict__ b, int n) {
  int i = blockIdx.x * 256 + threadIdx.x;
  if (i < n) { a[i] = 0; b[i] = 0; }
}
__global__ __launch_bounds__(256) void zero_f(float* __restrict__ p, int n) {
  int i = blockIdx.x * 256 + threadIdx.x;
  if (i < n) p[i] = 0.f;
}
__global__ __launch_bounds__(256) void hist_k(const int* __restrict__ dst, int* __restrict__ cnt, int e) {
  int i = blockIdx.x * 256 + threadIdx.x;
  if (i < e) atomicAdd(&cnt[dst[i]], 1);
}
__global__ __launch_bounds__(1024) void scan_block_k(const int* __restrict__ cnt, int* __restrict__ excl,
                                                     int* __restrict__ bsum, int n) {
  __shared__ int tmp[1024];
  int t = threadIdx.x;
  int i = blockIdx.x * 1024 + t;
  int v = (i < n) ? cnt[i] : 0;
  tmp[t] = v;
  __syncthreads();
  for (int off = 1; off < 1024; off <<= 1) {
    int add = (t >= off) ? tmp[t - off] : 0;
    __syncthreads();
    tmp[t] += add;
    __syncthreads();
  }
  if (i < n) excl[i] = tmp[t] - v;
  if (t == 1023) bsum[blockIdx.x] = tmp[1023];
}
__global__ void scan_bsum_k(int* __restrict__ bsum, int nb) {
  if (threadIdx.x == 0 && blockIdx.x == 0) {
    int run = 0;
    for (int b = 0; b < nb; b++) { int x = bsum[b]; bsum[b] = run; run += x; }
  }
}
__global__ __launch_bounds__(256) void finalize_rowptr_k(const int* __restrict__ excl, const int* __restrict__ bsum,
                                                         int* __restrict__ rowp, int n, int e) {
  int i = blockIdx.x * 256 + threadIdx.x;
  if (i < n) rowp[i] = excl[i] + bsum[i >> 10];
  if (i == 0) rowp[n] = e;
}
__global__ __launch_bounds__(256) void scatter_k(const int* __restrict__ src, const int* __restrict__ dst,
                                                 const int* __restrict__ rowp, int* __restrict__ cur,
                                                 int* __restrict__ srt, int e) {
  int i = blockIdx.x * 256 + threadIdx.x;
  if (i < e) {
    int d = dst[i];
    int pos = rowp[d] + atomicAdd(&cur[d], 1);
    srt[pos] = src[i];
  }
}

// ---------------- GEMM: out[n,OUTW] = A[n,K] @ W[K,OUTW] + bias ----------------
// Weight column in VGPRs; ROWS rows per thread (independent FMA chains);
// A read as wave-uniform float4 (scalar loads), amortized over ROWS rows.
template <int OUTW, int K, int ROWS>
__global__ __launch_bounds__(256) void gemm_k(const float* __restrict__ A, const float* __restrict__ W,
                                              const float* __restrict__ bias, float* __restrict__ out,
                                              int n, int rows_per_block) {
  constexpr int RG = 256 / OUTW;  // row-groups per block
  int c = threadIdx.x % OUTW;
  int rg = __builtin_amdgcn_readfirstlane((int)(threadIdx.x / OUTW));
  float w[K];
#pragma unroll
  for (int kk = 0; kk < K; kk++) w[kk] = W[kk * OUTW + c];
  float b = bias[c];
  int r0 = blockIdx.x * rows_per_block;
  int r1 = r0 + rows_per_block;
  if (r1 > n) r1 = n;
  for (int r = r0 + rg * ROWS; r < r1; r += RG * ROWS) {
    float acc[ROWS];
#pragma unroll
    for (int rr = 0; rr < ROWS; rr++) acc[rr] = b;
    int rowc[ROWS];
#pragma unroll
    for (int rr = 0; rr < ROWS; rr++) {
      int row = r + rr;
      rowc[rr] = (row < n) ? row : (n - 1);  // clamp (store guarded below)
    }
#pragma unroll
    for (int kq = 0; kq < K / 4; kq++) {
      float4 a4[ROWS];
#pragma unroll
      for (int rr = 0; rr < ROWS; rr++)
        a4[rr] = *(const float4*)(A + (size_t)rowc[rr] * K + kq * 4);
#pragma unroll
      for (int rr = 0; rr < ROWS; rr++) {
        acc[rr] = fmaf(a4[rr].x, w[kq * 4 + 0], acc[rr]);
        acc[rr] = fmaf(a4[rr].y, w[kq * 4 + 1], acc[rr]);
        acc[rr] = fmaf(a4[rr].z, w[kq * 4 + 2], acc[rr]);
        acc[rr] = fmaf(a4[rr].w, w[kq * 4 + 3], acc[rr]);
      }
    }
#pragma unroll
    for (int rr = 0; rr < ROWS; rr++) {
      int row = r + rr;
      if (row < r1) out[(size_t)row * OUTW + c] = acc[rr];
    }
  }
}

// ---------------- fused attention + head-mean + skip + relu ----------------
__global__ __launch_bounds__(256) void attn_k(const float* __restrict__ q, const float* __restrict__ kx,
                                              const float* __restrict__ vx, const float* __restrict__ sk,
                                              const int* __restrict__ rowp, const int* __restrict__ srt,
                                              float* __restrict__ hn, int n) {
  int wv = __builtin_amdgcn_readfirstlane((int)(threadIdx.x >> 6));
  int node = blockIdx.x * 4 + wv;
  if (node >= n) return;
  int lane = threadIdx.x & 63;
  int hd = lane >> 4;
  int c0 = (lane & 15) << 2;
  const float4 q4 = *(const float4*)(q + (size_t)node * 256 + hd * 64 + c0);
  float qx = q4.x * 0.125f, qy = q4.y * 0.125f, qz = q4.z * 0.125f, qw = q4.w * 0.125f;  // scale=1/sqrt(64)
  int rs = rowp[node], re = rowp[node + 1];
  float m = -INFINITY, d = 0.f;
  float ax = 0.f, ay = 0.f, az = 0.f, aw = 0.f;
  for (int i = rs; i < re; i++) {
    int sidx = srt[i];  // wave-uniform -> s_load
    const float4 k4 = *(const float4*)(kx + (size_t)sidx * 256 + hd * 64 + c0);
    float t = qx * k4.x + qy * k4.y + qz * k4.z + qw * k4.w;
    t += __shfl_xor(t, 1);
    t += __shfl_xor(t, 2);
    t += __shfl_xor(t, 4);
    t += __shfl_xor(t, 8);  // per-16-lane (per-head) dot reduce
    float mn = fmaxf(m, t);
    float co = __expf(m - mn);  // m=-inf first iter -> co=0
    float p = __expf(t - mn);
    d = d * co + p;
    const float4 v4 = *(const float4*)(vx + (size_t)sidx * 256 + hd * 64 + c0);
    ax = ax * co + p * v4.x;
    ay = ay * co + p * v4.y;
    az = az * co + p * v4.z;
    aw = aw * co + p * v4.w;
    m = mn;
  }
  float rx, ry, rz, rw;
  if (d > 0.f) {
    float inv = 1.f / d;
    rx = ax * inv; ry = ay * inv; rz = az * inv; rw = aw * inv;
  } else {
    rx = ry = rz = rw = 0.f;
  }
  rx += __shfl_xor(rx, 16); rx += __shfl_xor(rx, 32);
  ry += __shfl_xor(ry, 16); ry += __shfl_xor(ry, 32);
  rz += __shfl_xor(rz, 16); rz += __shfl_xor(rz, 32);
  rw += __shfl_xor(rw, 16); rw += __shfl_xor(rw, 32);
  if (hd == 0) {
    const float4 s4 = *(const float4*)(sk + (size_t)node * 64 + c0);
    float4 o;
    o.x = fmaxf(rx * 0.25f + s4.x, 0.f);
    o.y = fmaxf(ry * 0.25f + s4.y, 0.f);
    o.z = fmaxf(rz * 0.25f + s4.z, 0.f);
    o.w = fmaxf(rw * 0.25f + s4.w, 0.f);
    *(float4*)(hn + (size_t)node * 64 + c0) = o;
  }
}

// ---------------- global add pool (run-length; batch is sorted) ----------------
#define POOL_NPB 128
__global__ __launch_bounds__(64) void pool_k(const float* __restrict__ h, const int* __restrict__ batch,
                                             float* __restrict__ out, int n) {
  int c = threadIdx.x;
  int n0 = blockIdx.x * POOL_NPB;
  int n1 = n0 + POOL_NPB;
  if (n1 > n) n1 = n;
  if (n0 >= n) return;
  float acc = 0.f;
  int g = batch[n0];
  for (int node = n0; node < n1; node++) {
    int gb = batch[node];
    if (gb != g) {
      atomicAdd(&out[g * 64 + c], acc);
      acc = 0.f;
      g = gb;
    }
    acc += h[(size_t)node * 64 + c];
  }
  atomicAdd(&out[g * 64 + c], acc);
}

extern "C" void kernel_launch(void* const* d_in, const int* in_sizes, int n_in,
                              void* d_out, int out_size, void* d_ws, size_t ws_size,
                              hipStream_t stream) {
  const float* x  = (const float*)d_in[0];
  const int* ei   = (const int*)d_in[1];
  const int* batch = (const int*)d_in[2];
  const float* w0 = (const float*)d_in[3];
  const float* b0 = (const float*)d_in[4];
  const float* Wq = (const float*)d_in[5];
  const float* bq = (const float*)d_in[6];
  const float* Wk = (const float*)d_in[7];
  const float* bk = (const float*)d_in[8];
  const float* Wv = (const float*)d_in[9];
  const float* bv = (const float*)d_in[10];
  const float* Ws = (const float*)d_in[11];
  const float* bs = (const float*)d_in[12];
  int N = in_sizes[0] / F_IN;
  int E = in_sizes[1] / 2;
  const int* esrc = ei;
  const int* edst = ei + E;

  float* f = (float*)d_ws;
  float* h0 = f;
  float* h1 = h0 + (size_t)N * HID;
  float* q  = h1 + (size_t)N * HID;
  float* k  = q + (size_t)N * HID * NHEAD;
  float* v  = k + (size_t)N * HID * NHEAD;
  float* sb = v + (size_t)N * HID * NHEAD;
  int* cnt  = (int*)(sb + (size_t)N * HID);
  int* cur  = cnt + N;
  int* excl = cur + N;
  int* rowp = excl + N;
  int* bsum = rowp + N + 1;
  int* srt  = bsum + 64;

  int nbN = (N + 255) / 256;
  int nbE = (E + 255) / 256;
  int sbBlocks = (N + 1023) / 1024;

  zero_ints<<<nbN, 256, 0, stream>>>(cnt, cur, N);
  hist_k<<<nbE, 256, 0, stream>>>(edst, cnt, E);
  scan_block_k<<<sbBlocks, 1024, 0, stream>>>(cnt, excl, bsum, N);
  scan_bsum_k<<<1, 64, 0, stream>>>(bsum, sbBlocks);
  finalize_rowptr_k<<<nbN, 256, 0, stream>>>(excl, bsum, rowp, N, E);
  scatter_k<<<nbE, 256, 0, stream>>>(esrc, edst, rowp, cur, srt, E);

  const int RPB = 32;
  int gBlocks = (N + RPB - 1) / RPB;

  // h0 = x @ lin0_w + lin0_b  (K=128 -> ROWS=2 to limit register pressure)
  gemm_k<HID, F_IN, 2><<<gBlocks, 256, 0, stream>>>(x, w0, b0, h0, N, RPB);

  float* hc = h0;
  float* hx = h1;
  for (int l = 0; l < NLAYER; l++) {
    const size_t wOff = (size_t)l * HID * (NHEAD * HID);
    gemm_k<256, HID, 4><<<gBlocks, 256, 0, stream>>>(hc, Wq + wOff, bq + l * 256, q, N, RPB);
    gemm_k<256, HID, 4><<<gBlocks, 256, 0, stream>>>(hc, Wk + wOff, bk + l * 256, k, N, RPB);
    gemm_k<256, HID, 4><<<gBlocks, 256, 0, stream>>>(hc, Wv + wOff, bv + l * 256, v, N, RPB);
    gemm_k<HID, HID, 4><<<gBlocks, 256, 0, stream>>>(hc, Ws + (size_t)l * HID * HID, bs + l * HID, sb, N, RPB);
    attn_k<<<(N + 3) / 4, 256, 0, stream>>>(q, k, v, sb, rowp, srt, hx, N);
    float* t = hc; hc = hx; hx = t;
  }

  zero_f<<<(out_size + 255) / 256, 256, 0, stream>>>((float*)d_out, out_size);
  pool_k<<<(N + POOL_NPB - 1) / POOL_NPB, 64, 0, stream>>>(hc, batch, (float*)d_out, N);
}

// Round 3
// 404.953 us; speedup vs baseline: 3.2761x; 2.8591x over previous
//
#include <hip/hip_runtime.h>
#include <math.h>

#define F_IN 128
#define HID 64
#define NHEAD 4
#define NLAYER 3

typedef unsigned short ushort_t;
typedef __bf16 bf16x8 __attribute__((ext_vector_type(8)));
typedef float f32x4 __attribute__((ext_vector_type(4)));

__device__ __forceinline__ ushort_t f2bf(float f) {
  unsigned u = __float_as_uint(f);
  u += 0x7fffu + ((u >> 16) & 1u);  // RNE; inputs finite
  return (ushort_t)(u >> 16);
}
__device__ __forceinline__ float bf2f(ushort_t s) {
  return __uint_as_float(((unsigned)s) << 16);
}

// ---------------- CSR build ----------------
__global__ __launch_bounds__(256) void zero_ints(int* __restrict__ a, int* __restrict__ b, int n) {
  int i = blockIdx.x * 256 + threadIdx.x;
  if (i < n) { a[i] = 0; b[i] = 0; }
}
__global__ __launch_bounds__(256) void zero_f(float* __restrict__ p, int n) {
  int i = blockIdx.x * 256 + threadIdx.x;
  if (i < n) p[i] = 0.f;
}
__global__ __launch_bounds__(256) void hist_k(const int* __restrict__ dst, int* __restrict__ cnt, int e) {
  int i = blockIdx.x * 256 + threadIdx.x;
  if (i < e) atomicAdd(&cnt[dst[i]], 1);
}
__global__ __launch_bounds__(1024) void scan_block_k(const int* __restrict__ cnt, int* __restrict__ excl,
                                                     int* __restrict__ bsum, int n) {
  __shared__ int tmp[1024];
  int t = threadIdx.x;
  int i = blockIdx.x * 1024 + t;
  int v = (i < n) ? cnt[i] : 0;
  tmp[t] = v;
  __syncthreads();
  for (int off = 1; off < 1024; off <<= 1) {
    int add = (t >= off) ? tmp[t - off] : 0;
    __syncthreads();
    tmp[t] += add;
    __syncthreads();
  }
  if (i < n) excl[i] = tmp[t] - v;
  if (t == 1023) bsum[blockIdx.x] = tmp[1023];
}
__global__ void scan_bsum_k(int* __restrict__ bsum, int nb) {
  if (threadIdx.x == 0 && blockIdx.x == 0) {
    int run = 0;
    for (int b = 0; b < nb; b++) { int x = bsum[b]; bsum[b] = run; run += x; }
  }
}
__global__ __launch_bounds__(256) void finalize_rowptr_k(const int* __restrict__ excl, const int* __restrict__ bsum,
                                                         int* __restrict__ rowp, int n, int e) {
  int i = blockIdx.x * 256 + threadIdx.x;
  if (i < n) rowp[i] = excl[i] + bsum[i >> 10];
  if (i == 0) rowp[n] = e;
}
__global__ __launch_bounds__(256) void scatter_k(const int* __restrict__ src, const int* __restrict__ dst,
                                                 const int* __restrict__ rowp, int* __restrict__ cur,
                                                 int* __restrict__ srt, int e) {
  int i = blockIdx.x * 256 + threadIdx.x;
  if (i < e) {
    int d = dst[i];
    int pos = rowp[d] + atomicAdd(&cur[d], 1);
    srt[pos] = src[i];
  }
}

// ---------------- casts & weight packing ----------------
__global__ __launch_bounds__(256) void cast_f2b_k(const float* __restrict__ in, ushort_t* __restrict__ out,
                                                  long long n4) {
  long long i = ((long long)blockIdx.x * 256 + threadIdx.x) * 4;
  if (i < n4 * 4) {
    float4 f = *(const float4*)(in + i);
    ushort4 o;
    o.x = f2bf(f.x); o.y = f2bf(f.y); o.z = f2bf(f.z); o.w = f2bf(f.w);
    *(ushort4*)(out + i) = o;
  }
}

// Pack W[K,OUTW] (fp32 row-major) into MFMA B-fragment tiles:
// tile (nt,kt): lane l holds W[kt*32+(l>>4)*8+e][nt*16+(l&15)], e=0..7 (short8/lane).
__global__ __launch_bounds__(64) void pack_w1(const float* __restrict__ W, ushort_t* __restrict__ out,
                                              int K, int OUTW, long long wStride, long long oStride) {
  int l = blockIdx.y;
  const float* Wl = W + (long long)l * wStride;
  ushort_t* ol = out + (long long)l * oStride;
  int ktn = K >> 5;
  int tile = blockIdx.x;
  int nt = tile / ktn, kt = tile % ktn;
  int lane = threadIdx.x;
  int col = nt * 16 + (lane & 15);
  int kb = kt * 32 + (lane >> 4) * 8;
  ushort_t vals[8];
#pragma unroll
  for (int e = 0; e < 8; e++) vals[e] = f2bf(Wl[(long long)(kb + e) * OUTW + col]);
  ushort_t* p = ol + ((long long)tile * 64 + lane) * 8;
  ushort4 lo, hi;
  lo.x = vals[0]; lo.y = vals[1]; lo.z = vals[2]; lo.w = vals[3];
  hi.x = vals[4]; hi.y = vals[5]; hi.z = vals[6]; hi.w = vals[7];
  *(ushort4*)p = lo;
  *(ushort4*)(p + 4) = hi;
}

// Pack concatenated [Wq|Wk|Wv] (each [64,256]) -> 768-wide fragment buffer, per layer.
__global__ __launch_bounds__(64) void pack_qkv(const float* __restrict__ Wq, const float* __restrict__ Wk,
                                               const float* __restrict__ Wv, ushort_t* __restrict__ out) {
  int l = blockIdx.y;
  int tile = blockIdx.x;     // 96 tiles: nt 0..47, kt 0..1
  int nt = tile >> 1, kt = tile & 1;
  int lane = threadIdx.x;
  int col = nt * 16 + (lane & 15);
  int kb = kt * 32 + (lane >> 4) * 8;
  const float* Wsel = (col < 256) ? Wq : (col < 512 ? Wk : Wv);
  int c = col & 255;
  const float* Wl = Wsel + (long long)l * 64 * 256;
  ushort_t vals[8];
#pragma unroll
  for (int e = 0; e < 8; e++) vals[e] = f2bf(Wl[(long long)(kb + e) * 256 + c]);
  ushort_t* p = out + (long long)l * (96 * 512) + ((long long)tile * 64 + lane) * 8;
  ushort4 lo, hi;
  lo.x = vals[0]; lo.y = vals[1]; lo.z = vals[2]; lo.w = vals[3];
  hi.x = vals[4]; hi.y = vals[5]; hi.z = vals[6]; hi.w = vals[7];
  *(ushort4*)p = lo;
  *(ushort4*)(p + 4) = hi;
}
__global__ __launch_bounds__(256) void pack_bias_k(const float* __restrict__ bq, const float* __restrict__ bk,
                                                   const float* __restrict__ bv, float* __restrict__ bp) {
  int l = blockIdx.y;
  int c = blockIdx.x * 256 + threadIdx.x;  // 0..767
  float v = (c < 256) ? bq[l * 256 + c] : (c < 512 ? bk[l * 256 + c - 256] : bv[l * 256 + c - 512]);
  bp[l * 768 + c] = v;
}

// ---------------- MFMA GEMM: C[n,OUTW](bf16) = A[n,K](bf16) @ W + bias ----------------
// 1 wave/block, 32 rows x 64 cols per wave. A frag: row=lane&15, k=(lane>>4)*8+e.
template <int K>
__global__ __launch_bounds__(64) void gemm_mfma(const ushort_t* __restrict__ A, const ushort_t* __restrict__ Wp,
                                                const float* __restrict__ bias, ushort_t* __restrict__ C,
                                                int n, int OUTW) {
  constexpr int KT = K / 32;
  int lane = threadIdx.x;
  int m0 = blockIdx.x * 32;
  int n0 = blockIdx.y * 64;
  int lr = lane & 15, lq = lane >> 4;

  bf16x8 a[2][KT];
#pragma unroll
  for (int mr = 0; mr < 2; mr++) {
    int row = m0 + mr * 16 + lr;
    if (row >= n) row = n - 1;
#pragma unroll
    for (int kt = 0; kt < KT; kt++)
      a[mr][kt] = *(const bf16x8*)(A + (long long)row * K + kt * 32 + lq * 8);
  }
  f32x4 acc[2][4];
#pragma unroll
  for (int nt = 0; nt < 4; nt++) {
    float b = bias[n0 + nt * 16 + lr];
    f32x4 b4 = {b, b, b, b};
    acc[0][nt] = b4;
    acc[1][nt] = b4;
  }
#pragma unroll
  for (int nt = 0; nt < 4; nt++) {
    int ntg = (n0 >> 4) + nt;
#pragma unroll
    for (int kt = 0; kt < KT; kt++) {
      bf16x8 bw = *(const bf16x8*)(Wp + ((long long)(ntg * KT + kt) * 64 + lane) * 8);
      acc[0][nt] = __builtin_amdgcn_mfma_f32_16x16x32_bf16(a[0][kt], bw, acc[0][nt], 0, 0, 0);
      acc[1][nt] = __builtin_amdgcn_mfma_f32_16x16x32_bf16(a[1][kt], bw, acc[1][nt], 0, 0, 0);
    }
  }
#pragma unroll
  for (int mr = 0; mr < 2; mr++)
#pragma unroll
    for (int nt = 0; nt < 4; nt++)
#pragma unroll
      for (int r = 0; r < 4; r++) {
        int row = m0 + mr * 16 + lq * 4 + r;
        if (row < n) C[(long long)row * OUTW + n0 + nt * 16 + lr] = f2bf(acc[mr][nt][r]);
      }
}

// ---------------- fused attention + head-mean + skip + relu (bf16 in/out) ----------------
// One wave/node; head = lane>>4, 4 channels/lane. 4-edge chunks: 8 independent loads in flight.
__global__ __launch_bounds__(256) void attn_k(const ushort_t* __restrict__ qkv, const ushort_t* __restrict__ sk,
                                              const int* __restrict__ rowp, const int* __restrict__ srt,
                                              ushort_t* __restrict__ hn, int n) {
  int wv = __builtin_amdgcn_readfirstlane((int)(threadIdx.x >> 6));
  int node = blockIdx.x * 4 + wv;
  if (node >= n) return;
  int lane = threadIdx.x & 63;
  int hd = lane >> 4;
  int c0 = (lane & 15) << 2;
  const ushort4 q4 = *(const ushort4*)(qkv + (long long)node * 768 + hd * 64 + c0);
  float qx = bf2f(q4.x) * 0.125f, qy = bf2f(q4.y) * 0.125f;
  float qz = bf2f(q4.z) * 0.125f, qw = bf2f(q4.w) * 0.125f;
  int rs = rowp[node], re = rowp[node + 1];
  float m = -INFINITY, d = 0.f;
  float ax = 0.f, ay = 0.f, az = 0.f, aw = 0.f;
  for (int i = rs; i < re; i += 4) {
    int last = re - 1;
    int idx0 = srt[i];
    int idx1 = srt[min(i + 1, last)];
    int idx2 = srt[min(i + 2, last)];
    int idx3 = srt[min(i + 3, last)];
    long long o0 = (long long)idx0 * 768 + hd * 64 + c0;
    long long o1 = (long long)idx1 * 768 + hd * 64 + c0;
    long long o2 = (long long)idx2 * 768 + hd * 64 + c0;
    long long o3 = (long long)idx3 * 768 + hd * 64 + c0;
    ushort4 k0 = *(const ushort4*)(qkv + o0 + 256);
    ushort4 k1 = *(const ushort4*)(qkv + o1 + 256);
    ushort4 k2 = *(const ushort4*)(qkv + o2 + 256);
    ushort4 k3 = *(const ushort4*)(qkv + o3 + 256);
    ushort4 v0 = *(const ushort4*)(qkv + o0 + 512);
    ushort4 v1 = *(const ushort4*)(qkv + o1 + 512);
    ushort4 v2 = *(const ushort4*)(qkv + o2 + 512);
    ushort4 v3 = *(const ushort4*)(qkv + o3 + 512);
    float t0 = qx * bf2f(k0.x) + qy * bf2f(k0.y) + qz * bf2f(k0.z) + qw * bf2f(k0.w);
    float t1 = qx * bf2f(k1.x) + qy * bf2f(k1.y) + qz * bf2f(k1.z) + qw * bf2f(k1.w);
    float t2 = qx * bf2f(k2.x) + qy * bf2f(k2.y) + qz * bf2f(k2.z) + qw * bf2f(k2.w);
    float t3 = qx * bf2f(k3.x) + qy * bf2f(k3.y) + qz * bf2f(k3.z) + qw * bf2f(k3.w);
    t0 += __shfl_xor(t0, 1); t0 += __shfl_xor(t0, 2); t0 += __shfl_xor(t0, 4); t0 += __shfl_xor(t0, 8);
    t1 += __shfl_xor(t1, 1); t1 += __shfl_xor(t1, 2); t1 += __shfl_xor(t1, 4); t1 += __shfl_xor(t1, 8);
    t2 += __shfl_xor(t2, 1); t2 += __shfl_xor(t2, 2); t2 += __shfl_xor(t2, 4); t2 += __shfl_xor(t2, 8);
    t3 += __shfl_xor(t3, 1); t3 += __shfl_xor(t3, 2); t3 += __shfl_xor(t3, 4); t3 += __shfl_xor(t3, 8);
    int cnt = re - i;
    if (cnt <= 3) t3 = -INFINITY;
    if (cnt <= 2) t2 = -INFINITY;
    if (cnt <= 1) t1 = -INFINITY;
    float mn = fmaxf(fmaxf(fmaxf(t0, t1), fmaxf(t2, t3)), m);
    float co = __expf(m - mn);  // m=-inf first chunk -> co=0
    float p0 = __expf(t0 - mn), p1 = __expf(t1 - mn), p2 = __expf(t2 - mn), p3 = __expf(t3 - mn);
    d = d * co + ((p0 + p1) + (p2 + p3));
    ax = ax * co + (p0 * bf2f(v0.x) + p1 * bf2f(v1.x) + p2 * bf2f(v2.x) + p3 * bf2f(v3.x));
    ay = ay * co + (p0 * bf2f(v0.y) + p1 * bf2f(v1.y) + p2 * bf2f(v2.y) + p3 * bf2f(v3.y));
    az = az * co + (p0 * bf2f(v0.z) + p1 * bf2f(v1.z) + p2 * bf2f(v2.z) + p3 * bf2f(v3.z));
    aw = aw * co + (p0 * bf2f(v0.w) + p1 * bf2f(v1.w) + p2 * bf2f(v2.w) + p3 * bf2f(v3.w));
    m = mn;
  }
  float rx, ry, rz, rw;
  if (d > 0.f) {
    float inv = 1.f / d;
    rx = ax * inv; ry = ay * inv; rz = az * inv; rw = aw * inv;
  } else {
    rx = ry = rz = rw = 0.f;
  }
  rx += __shfl_xor(rx, 16); rx += __shfl_xor(rx, 32);
  ry += __shfl_xor(ry, 16); ry += __shfl_xor(ry, 32);
  rz += __shfl_xor(rz, 16); rz += __shfl_xor(rz, 32);
  rw += __shfl_xor(rw, 16); rw += __shfl_xor(rw, 32);
  if (hd == 0) {
    const ushort4 s4 = *(const ushort4*)(sk + (long long)node * 64 + c0);
    ushort4 o;
    o.x = f2bf(fmaxf(rx * 0.25f + bf2f(s4.x), 0.f));
    o.y = f2bf(fmaxf(ry * 0.25f + bf2f(s4.y), 0.f));
    o.z = f2bf(fmaxf(rz * 0.25f + bf2f(s4.z), 0.f));
    o.w = f2bf(fmaxf(rw * 0.25f + bf2f(s4.w), 0.f));
    *(ushort4*)(hn + (long long)node * 64 + c0) = o;
  }
}

// ---------------- global add pool (run-length; batch is sorted) ----------------
#define POOL_NPB 128
__global__ __launch_bounds__(64) void pool_k(const ushort_t* __restrict__ h, const int* __restrict__ batch,
                                             float* __restrict__ out, int n) {
  int c = threadIdx.x;
  int n0 = blockIdx.x * POOL_NPB;
  int n1 = n0 + POOL_NPB;
  if (n1 > n) n1 = n;
  if (n0 >= n) return;
  float acc = 0.f;
  int g = batch[n0];
  for (int node = n0; node < n1; node++) {
    int gb = batch[node];
    if (gb != g) {
      atomicAdd(&out[g * 64 + c], acc);
      acc = 0.f;
      g = gb;
    }
    acc += bf2f(h[(long long)node * 64 + c]);
  }
  atomicAdd(&out[g * 64 + c], acc);
}

extern "C" void kernel_launch(void* const* d_in, const int* in_sizes, int n_in,
                              void* d_out, int out_size, void* d_ws, size_t ws_size,
                              hipStream_t stream) {
  const float* x  = (const float*)d_in[0];
  const int* ei   = (const int*)d_in[1];
  const int* batch = (const int*)d_in[2];
  const float* w0 = (const float*)d_in[3];
  const float* b0 = (const float*)d_in[4];
  const float* Wq = (const float*)d_in[5];
  const float* bq = (const float*)d_in[6];
  const float* Wk = (const float*)d_in[7];
  const float* bk = (const float*)d_in[8];
  const float* Wv = (const float*)d_in[9];
  const float* bv = (const float*)d_in[10];
  const float* Ws = (const float*)d_in[11];
  const float* bs = (const float*)d_in[12];
  int N = in_sizes[0] / F_IN;
  int E = in_sizes[1] / 2;
  const int* esrc = ei;
  const int* edst = ei + E;

  // ---- workspace layout ----
  float* bp = (float*)d_ws;                              // 3*768 fp32 qkv bias
  ushort_t* x_bf   = (ushort_t*)(bp + 3 * 768);
  ushort_t* h0     = x_bf + (long long)N * 128;
  ushort_t* h1     = h0 + (long long)N * 64;
  ushort_t* qkvb   = h1 + (long long)N * 64;
  ushort_t* sb     = qkvb + (long long)N * 768;
  ushort_t* wp_lin0 = sb + (long long)N * 64;            // 16 tiles * 512
  ushort_t* wp_qkv  = wp_lin0 + 16 * 512;                // 3 * 96 * 512
  ushort_t* wp_s    = wp_qkv + 3 * 96 * 512;             // 3 * 8 * 512
  int* cnt  = (int*)(wp_s + 3 * 8 * 512);
  int* cur  = cnt + N;
  int* excl = cur + N;
  int* rowp = excl + N;
  int* bsum = rowp + N + 1;
  int* srt  = bsum + 64;

  int nbN = (N + 255) / 256;
  int nbE = (E + 255) / 256;
  int sbBlocks = (N + 1023) / 1024;

  // CSR by dst
  zero_ints<<<nbN, 256, 0, stream>>>(cnt, cur, N);
  hist_k<<<nbE, 256, 0, stream>>>(edst, cnt, E);
  scan_block_k<<<sbBlocks, 1024, 0, stream>>>(cnt, excl, bsum, N);
  scan_bsum_k<<<1, 64, 0, stream>>>(bsum, sbBlocks);
  finalize_rowptr_k<<<nbN, 256, 0, stream>>>(excl, bsum, rowp, N, E);
  scatter_k<<<nbE, 256, 0, stream>>>(esrc, edst, rowp, cur, srt, E);

  // casts + weight packing
  long long n4 = (long long)N * 128 / 4;
  cast_f2b_k<<<(int)((n4 + 255) / 256), 256, 0, stream>>>(x, x_bf, n4);
  pack_w1<<<dim3(16, 1), 64, 0, stream>>>(w0, wp_lin0, 128, 64, 0, 0);
  pack_w1<<<dim3(8, 3), 64, 0, stream>>>(Ws, wp_s, 64, 64, 64 * 64, 8 * 512);
  pack_qkv<<<dim3(96, 3), 64, 0, stream>>>(Wq, Wk, Wv, wp_qkv);
  pack_bias_k<<<dim3(3, 3), 256, 0, stream>>>(bq, bk, bv, bp);

  int mBlocks = (N + 31) / 32;

  // h0 = x @ lin0_w + lin0_b
  gemm_mfma<128><<<dim3(mBlocks, 1), 64, 0, stream>>>(x_bf, wp_lin0, b0, h0, N, 64);

  ushort_t* hc = h0;
  ushort_t* hx = h1;
  for (int l = 0; l < NLAYER; l++) {
    gemm_mfma<64><<<dim3(mBlocks, 12), 64, 0, stream>>>(hc, wp_qkv + (long long)l * 96 * 512,
                                                        bp + l * 768, qkvb, N, 768);
    gemm_mfma<64><<<dim3(mBlocks, 1), 64, 0, stream>>>(hc, wp_s + (long long)l * 8 * 512,
                                                       bs + l * 64, sb, N, 64);
    attn_k<<<(N + 3) / 4, 256, 0, stream>>>(qkvb, sb, rowp, srt, hx, N);
    ushort_t* t = hc; hc = hx; hx = t;
  }

  zero_f<<<(out_size + 255) / 256, 256, 0, stream>>>((float*)d_out, out_size);
  pool_k<<<(N + POOL_NPB - 1) / POOL_NPB, 64, 0, stream>>>(hc, batch, (float*)d_out, N);
}

// Round 4
// 382.518 us; speedup vs baseline: 3.4682x; 1.0587x over previous
//
#include <hip/hip_runtime.h>
#include <math.h>

#define F_IN 128
#define HID 64
#define NHEAD 4
#define NLAYER 3
#define QSW 832  // unified row: q(256)|k(256)|v(256)|skip(64)

typedef unsigned short ushort_t;
typedef __bf16 bf16x8 __attribute__((ext_vector_type(8)));
typedef unsigned short u16x8 __attribute__((ext_vector_type(8)));
typedef float f32x4 __attribute__((ext_vector_type(4)));

__device__ __forceinline__ ushort_t f2bf(float f) {
  unsigned u = __float_as_uint(f);
  u += 0x7fffu + ((u >> 16) & 1u);  // RNE; inputs finite
  return (ushort_t)(u >> 16);
}
__device__ __forceinline__ float bf2f(ushort_t s) {
  return __uint_as_float(((unsigned)s) << 16);
}

// ---------------- CSR build ----------------
__global__ __launch_bounds__(256) void zero_ints(int* __restrict__ a, int* __restrict__ b, int n) {
  int i = blockIdx.x * 256 + threadIdx.x;
  if (i < n) { a[i] = 0; b[i] = 0; }
}
__global__ __launch_bounds__(256) void hist_k(const int* __restrict__ dst, int* __restrict__ cnt, int e) {
  int i = blockIdx.x * 256 + threadIdx.x;
  if (i < e) atomicAdd(&cnt[dst[i]], 1);
}
__global__ __launch_bounds__(1024) void scan_block_k(const int* __restrict__ cnt, int* __restrict__ excl,
                                                     int* __restrict__ bsum, int n) {
  __shared__ int tmp[1024];
  int t = threadIdx.x;
  int i = blockIdx.x * 1024 + t;
  int v = (i < n) ? cnt[i] : 0;
  tmp[t] = v;
  __syncthreads();
  for (int off = 1; off < 1024; off <<= 1) {
    int add = (t >= off) ? tmp[t - off] : 0;
    __syncthreads();
    tmp[t] += add;
    __syncthreads();
  }
  if (i < n) excl[i] = tmp[t] - v;
  if (t == 1023) bsum[blockIdx.x] = tmp[1023];
}
// parallel exclusive scan of block sums (nb <= 64)
__global__ __launch_bounds__(64) void scan_bsum_k(int* __restrict__ bsum, int nb) {
  int l = threadIdx.x;
  int orig = (l < nb) ? bsum[l] : 0;
  int v = orig;
  for (int off = 1; off < 64; off <<= 1) {
    int u = __shfl_up(v, off);
    if (l >= off) v += u;
  }
  if (l < nb) bsum[l] = v - orig;
}
__global__ __launch_bounds__(256) void finalize_rowptr_k(const int* __restrict__ excl, const int* __restrict__ bsum,
                                                         int* __restrict__ rowp, int n, int e) {
  int i = blockIdx.x * 256 + threadIdx.x;
  if (i < n) rowp[i] = excl[i] + bsum[i >> 10];
  if (i == 0) rowp[n] = e;
}
__global__ __launch_bounds__(256) void scatter_k(const int* __restrict__ src, const int* __restrict__ dst,
                                                 const int* __restrict__ rowp, int* __restrict__ cur,
                                                 int* __restrict__ srt, int e) {
  int i = blockIdx.x * 256 + threadIdx.x;
  if (i < e) {
    int d = dst[i];
    int pos = rowp[d] + atomicAdd(&cur[d], 1);
    srt[pos] = src[i];
  }
}

// ---------------- weight / bias packing ----------------
// wp layout: frag tile t=(ntg*KT+kt): lane l holds W[kt*32+(l>>4)*8+e][ntg*16+(l&15)]
// Blocks 0..311: per-layer [Wq|Wk|Wv|Ws] -> 832-wide, KT=2 (104 tiles/layer).
// Blocks 312..327: lin0 [128,64], KT=4 (16 tiles).
__global__ __launch_bounds__(64) void pack_weights(const float* __restrict__ Wq, const float* __restrict__ Wk,
                                                   const float* __restrict__ Wv, const float* __restrict__ Ws,
                                                   const float* __restrict__ w0, ushort_t* __restrict__ wp_all,
                                                   ushort_t* __restrict__ wp_lin0) {
  int b = blockIdx.x, lane = threadIdx.x;
  if (b < 312) {
    int l = b / 104, t = b % 104;
    int ntg = t >> 1, kt = t & 1;
    int col = ntg * 16 + (lane & 15);
    int kb = kt * 32 + (lane >> 4) * 8;
    const float* W;
    int c, stride;
    if (col < 256)      { W = Wq + (long long)l * 64 * 256; c = col;       stride = 256; }
    else if (col < 512) { W = Wk + (long long)l * 64 * 256; c = col - 256; stride = 256; }
    else if (col < 768) { W = Wv + (long long)l * 64 * 256; c = col - 512; stride = 256; }
    else                { W = Ws + (long long)l * 64 * 64;  c = col - 768; stride = 64; }
    ushort_t vals[8];
#pragma unroll
    for (int e = 0; e < 8; e++) vals[e] = f2bf(W[(long long)(kb + e) * stride + c]);
    ushort_t* p = wp_all + (long long)l * (104 * 512) + ((long long)t * 64 + lane) * 8;
    ushort4 lo{vals[0], vals[1], vals[2], vals[3]}, hi{vals[4], vals[5], vals[6], vals[7]};
    *(ushort4*)p = lo;
    *(ushort4*)(p + 4) = hi;
  } else {
    int t = b - 312;  // 0..15: ntg=t>>2, kt=t&3
    int col = (t >> 2) * 16 + (lane & 15);
    int kb = (t & 3) * 32 + (lane >> 4) * 8;
    ushort_t vals[8];
#pragma unroll
    for (int e = 0; e < 8; e++) vals[e] = f2bf(w0[(long long)(kb + e) * 64 + col]);
    ushort_t* p = wp_lin0 + ((long long)t * 64 + lane) * 8;
    ushort4 lo{vals[0], vals[1], vals[2], vals[3]}, hi{vals[4], vals[5], vals[6], vals[7]};
    *(ushort4*)p = lo;
    *(ushort4*)(p + 4) = hi;
  }
}
__global__ __launch_bounds__(832) void pack_bias_k(const float* __restrict__ bq, const float* __restrict__ bk,
                                                   const float* __restrict__ bv, const float* __restrict__ bs,
                                                   float* __restrict__ bp) {
  int l = blockIdx.x, c = threadIdx.x;
  float v = (c < 256) ? bq[l * 256 + c]
          : (c < 512) ? bk[l * 256 + c - 256]
          : (c < 768) ? bv[l * 256 + c - 512]
          : bs[l * 64 + c - 768];
  bp[l * QSW + c] = v;
}

// ---------------- MFMA GEMM: C[n,outw](bf16) = A[n,K] @ W + bias ----------------
// 4 waves/block, each wave 32 rows x 64 cols. A frag: row=lane&15, k=(lane>>4)*8+e.
template <int K, int AF32>
__global__ __launch_bounds__(256) void gemm_mfma(const void* __restrict__ Av, const ushort_t* __restrict__ Wp,
                                                 const float* __restrict__ bias, ushort_t* __restrict__ C,
                                                 int n, int outw) {
  constexpr int KT = K / 32;
  int lane = threadIdx.x & 63;
  int wv = __builtin_amdgcn_readfirstlane((int)(threadIdx.x >> 6));
  int m0 = blockIdx.x * 128 + wv * 32;
  int n0 = blockIdx.y * 64;
  int lr = lane & 15, lq = lane >> 4;

  bf16x8 a[2][KT];
#pragma unroll
  for (int mr = 0; mr < 2; mr++) {
    int row = m0 + mr * 16 + lr;
    if (row >= n) row = n - 1;
    if constexpr (AF32) {
      const float* Af = (const float*)Av;
#pragma unroll
      for (int kt = 0; kt < KT; kt++) {
        const float* p = Af + (long long)row * K + kt * 32 + lq * 8;
        float4 f0 = *(const float4*)p;
        float4 f1 = *(const float4*)(p + 4);
        u16x8 u;
        u[0] = f2bf(f0.x); u[1] = f2bf(f0.y); u[2] = f2bf(f0.z); u[3] = f2bf(f0.w);
        u[4] = f2bf(f1.x); u[5] = f2bf(f1.y); u[6] = f2bf(f1.z); u[7] = f2bf(f1.w);
        a[mr][kt] = __builtin_bit_cast(bf16x8, u);
      }
    } else {
      const ushort_t* Ab = (const ushort_t*)Av;
#pragma unroll
      for (int kt = 0; kt < KT; kt++)
        a[mr][kt] = *(const bf16x8*)(Ab + (long long)row * K + kt * 32 + lq * 8);
    }
  }
  f32x4 acc[2][4];
#pragma unroll
  for (int nt = 0; nt < 4; nt++) {
    float b = bias[n0 + nt * 16 + lr];
    f32x4 b4 = {b, b, b, b};
    acc[0][nt] = b4;
    acc[1][nt] = b4;
  }
#pragma unroll
  for (int nt = 0; nt < 4; nt++) {
    int ntg = (n0 >> 4) + nt;
#pragma unroll
    for (int kt = 0; kt < KT; kt++) {
      bf16x8 bw = *(const bf16x8*)(Wp + ((long long)(ntg * KT + kt) * 64 + lane) * 8);
      acc[0][nt] = __builtin_amdgcn_mfma_f32_16x16x32_bf16(a[0][kt], bw, acc[0][nt], 0, 0, 0);
      acc[1][nt] = __builtin_amdgcn_mfma_f32_16x16x32_bf16(a[1][kt], bw, acc[1][nt], 0, 0, 0);
    }
  }
#pragma unroll
  for (int mr = 0; mr < 2; mr++)
#pragma unroll
    for (int nt = 0; nt < 4; nt++)
#pragma unroll
      for (int r = 0; r < 4; r++) {
        int row = m0 + mr * 16 + lq * 4 + r;
        if (row < n) C[(long long)row * outw + n0 + nt * 16 + lr] = f2bf(acc[mr][nt][r]);
      }
}

// ---------------- fused attention + head-mean + skip + relu ----------------
// One wave/node. lane = half*32 + head*8 + c8 (8 channels/lane, bf16x8 16B loads).
// Per iteration: 4 edges (2 per half), K rows loaded 2-per-instruction.
__global__ __launch_bounds__(256) void attn_k(const ushort_t* __restrict__ qs,
                                              const int* __restrict__ rowp, const int* __restrict__ srt,
                                              ushort_t* __restrict__ hn, int n) {
  int wvv = __builtin_amdgcn_readfirstlane((int)(threadIdx.x >> 6));
  int node = blockIdx.x * 4 + wvv;
  if (node >= n) return;
  int lane = threadIdx.x & 63;
  int half = lane >> 5;
  int sl = lane & 31;  // head = sl>>3, c8 = sl&7
  const u16x8 qv = *(const u16x8*)(qs + (long long)node * QSW + sl * 8);
  float qf[8];
#pragma unroll
  for (int j = 0; j < 8; j++) qf[j] = bf2f(qv[j]) * 0.125f;  // 1/sqrt(64)
  int rs = rowp[node], re = rowp[node + 1];
  float m = -INFINITY, d = 0.f;
  float a[8];
#pragma unroll
  for (int j = 0; j < 8; j++) a[j] = 0.f;
  int last = re - 1;
  for (int i = rs; i < re; i += 4) {
    int e0 = i + half, e1 = e0 + 2;
    int i0 = srt[e0 <= last ? e0 : last];
    int i1 = srt[e1 <= last ? e1 : last];
    const ushort_t* p0 = qs + (long long)i0 * QSW + sl * 8;
    const ushort_t* p1 = qs + (long long)i1 * QSW + sl * 8;
    u16x8 k0 = *(const u16x8*)(p0 + 256);
    u16x8 k1 = *(const u16x8*)(p1 + 256);
    u16x8 v0 = *(const u16x8*)(p0 + 512);
    u16x8 v1 = *(const u16x8*)(p1 + 512);
    float t0 = 0.f, t1 = 0.f;
#pragma unroll
    for (int j = 0; j < 8; j++) {
      t0 = fmaf(qf[j], bf2f(k0[j]), t0);
      t1 = fmaf(qf[j], bf2f(k1[j]), t1);
    }
    t0 += __shfl_xor(t0, 1); t1 += __shfl_xor(t1, 1);
    t0 += __shfl_xor(t0, 2); t1 += __shfl_xor(t1, 2);
    t0 += __shfl_xor(t0, 4); t1 += __shfl_xor(t1, 4);
    if (e0 > last) t0 = -INFINITY;
    if (e1 > last) t1 = -INFINITY;
    float t0x = __shfl_xor(t0, 32);
    float t1x = __shfl_xor(t1, 32);
    float mn = fmaxf(fmaxf(fmaxf(t0, t0x), fmaxf(t1, t1x)), m);
    float co = __expf(m - mn);  // first iter: -inf - finite -> 0
    float p0e = __expf(t0 - mn);
    float p1e = __expf(t1 - mn);
    d = d * co + p0e + p1e;
#pragma unroll
    for (int j = 0; j < 8; j++)
      a[j] = a[j] * co + fmaf(p0e, bf2f(v0[j]), p1e * bf2f(v1[j]));
    m = mn;
  }
  // merge halves (same head at lane^32)
  d += __shfl_xor(d, 32);
#pragma unroll
  for (int j = 0; j < 8; j++) a[j] += __shfl_xor(a[j], 32);
  float inv = (d > 0.f) ? 1.f / d : 0.f;
  float r[8];
#pragma unroll
  for (int j = 0; j < 8; j++) {
    r[j] = a[j] * inv;
    r[j] += __shfl_xor(r[j], 8);   // head ^1
    r[j] += __shfl_xor(r[j], 16);  // head ^2
  }
  if (lane < 8) {
    const u16x8 s8 = *(const u16x8*)(qs + (long long)node * QSW + 768 + lane * 8);
    u16x8 o;
#pragma unroll
    for (int j = 0; j < 8; j++)
      o[j] = f2bf(fmaxf(r[j] * 0.25f + bf2f(s8[j]), 0.f));
    *(u16x8*)(hn + (long long)node * HID + lane * 8) = o;
  }
}

// ---------------- global add pool (run-length; batch is sorted) ----------------
#define POOL_NPB 128
__global__ __launch_bounds__(64) void pool_k(const ushort_t* __restrict__ h, const int* __restrict__ batch,
                                             float* __restrict__ out, int n) {
  int c = threadIdx.x;
  int n0 = blockIdx.x * POOL_NPB;
  int n1 = n0 + POOL_NPB;
  if (n1 > n) n1 = n;
  if (n0 >= n) return;
  float acc = 0.f;
  int g = batch[n0];
  for (int node = n0; node < n1; node++) {
    int gb = batch[node];
    if (gb != g) {
      atomicAdd(&out[g * 64 + c], acc);
      acc = 0.f;
      g = gb;
    }
    acc += bf2f(h[(long long)node * 64 + c]);
  }
  atomicAdd(&out[g * 64 + c], acc);
}

extern "C" void kernel_launch(void* const* d_in, const int* in_sizes, int n_in,
                              void* d_out, int out_size, void* d_ws, size_t ws_size,
                              hipStream_t stream) {
  const float* x  = (const float*)d_in[0];
  const int* ei   = (const int*)d_in[1];
  const int* batch = (const int*)d_in[2];
  const float* w0 = (const float*)d_in[3];
  const float* b0 = (const float*)d_in[4];
  const float* Wq = (const float*)d_in[5];
  const float* bq = (const float*)d_in[6];
  const float* Wk = (const float*)d_in[7];
  const float* bk = (const float*)d_in[8];
  const float* Wv = (const float*)d_in[9];
  const float* bv = (const float*)d_in[10];
  const float* Ws = (const float*)d_in[11];
  const float* bs = (const float*)d_in[12];
  int N = in_sizes[0] / F_IN;
  int E = in_sizes[1] / 2;
  const int* esrc = ei;
  const int* edst = ei + E;

  // ---- workspace layout ----
  float* bp = (float*)d_ws;                               // 3*832 f32
  ushort_t* h0   = (ushort_t*)(bp + 3 * QSW);
  ushort_t* h1   = h0 + (long long)N * HID;
  ushort_t* qsb  = h1 + (long long)N * HID;               // N x 832
  ushort_t* wp_all  = qsb + (long long)N * QSW;           // 3 * 104 * 512
  ushort_t* wp_lin0 = wp_all + 3 * 104 * 512;             // 16 * 512
  int* cnt  = (int*)(wp_lin0 + 16 * 512);
  int* cur  = cnt + N;
  int* excl = cur + N;
  int* rowp = excl + N;
  int* bsum = rowp + N + 1;
  int* srt  = bsum + 64;

  int nbN = (N + 255) / 256;
  int nbE = (E + 255) / 256;
  int sbBlocks = (N + 1023) / 1024;

  // CSR by dst
  zero_ints<<<nbN, 256, 0, stream>>>(cnt, cur, N);
  hist_k<<<nbE, 256, 0, stream>>>(edst, cnt, E);
  scan_block_k<<<sbBlocks, 1024, 0, stream>>>(cnt, excl, bsum, N);
  scan_bsum_k<<<1, 64, 0, stream>>>(bsum, sbBlocks);
  finalize_rowptr_k<<<nbN, 256, 0, stream>>>(excl, bsum, rowp, N, E);
  scatter_k<<<nbE, 256, 0, stream>>>(esrc, edst, rowp, cur, srt, E);

  // weight/bias packing
  pack_weights<<<328, 64, 0, stream>>>(Wq, Wk, Wv, Ws, w0, wp_all, wp_lin0);
  pack_bias_k<<<3, 832, 0, stream>>>(bq, bk, bv, bs, bp);

  int mBlocks = (N + 127) / 128;

  // h0 = x @ lin0_w + lin0_b  (A fp32 direct)
  gemm_mfma<128, 1><<<dim3(mBlocks, 1), 256, 0, stream>>>(x, wp_lin0, b0, h0, N, HID);

  ushort_t* hc = h0;
  ushort_t* hx = h1;
  for (int l = 0; l < NLAYER; l++) {
    gemm_mfma<64, 0><<<dim3(mBlocks, 13), 256, 0, stream>>>(hc, wp_all + (long long)l * 104 * 512,
                                                            bp + l * QSW, qsb, N, QSW);
    attn_k<<<(N + 3) / 4, 256, 0, stream>>>(qsb, rowp, srt, hx, N);
    ushort_t* t = hc; hc = hx; hx = t;
  }

  hipMemsetAsync(d_out, 0, (size_t)out_size * sizeof(float), stream);
  pool_k<<<(N + POOL_NPB - 1) / POOL_NPB, 64, 0, stream>>>(hc, batch, (float*)d_out, N);
}

// Round 5
// 377.677 us; speedup vs baseline: 3.5127x; 1.0128x over previous
//
#include <hip/hip_runtime.h>
#include <math.h>

#define F_IN 128
#define HID 64
#define NHEAD 4
#define NLAYER 3
#define QSW 832  // unified row: q(256)|k(256)|v(256)|skip(64)

typedef unsigned short ushort_t;
typedef __bf16 bf16x8 __attribute__((ext_vector_type(8)));
typedef unsigned short u16x8 __attribute__((ext_vector_type(8)));
typedef float f32x4 __attribute__((ext_vector_type(4)));

__device__ __forceinline__ ushort_t f2bf(float f) {
  unsigned u = __float_as_uint(f);
  u += 0x7fffu + ((u >> 16) & 1u);  // RNE; inputs finite
  return (ushort_t)(u >> 16);
}
__device__ __forceinline__ float bf2f(ushort_t s) {
  return __uint_as_float(((unsigned)s) << 16);
}
__device__ __forceinline__ float blo(unsigned u) { return __uint_as_float(u << 16); }
__device__ __forceinline__ float bhi(unsigned u) { return __uint_as_float(u & 0xffff0000u); }

// ---------------- CSR build ----------------
__global__ __launch_bounds__(256) void hist_k(const int* __restrict__ dst, int* __restrict__ cnt, int e) {
  int i = blockIdx.x * 256 + threadIdx.x;
  if (i < e) atomicAdd(&cnt[dst[i]], 1);
}
__global__ __launch_bounds__(1024) void scan_block_k(const int* __restrict__ cnt, int* __restrict__ excl,
                                                     int* __restrict__ bsum, int n) {
  __shared__ int tmp[1024];
  int t = threadIdx.x;
  int i = blockIdx.x * 1024 + t;
  int v = (i < n) ? cnt[i] : 0;
  tmp[t] = v;
  __syncthreads();
  for (int off = 1; off < 1024; off <<= 1) {
    int add = (t >= off) ? tmp[t - off] : 0;
    __syncthreads();
    tmp[t] += add;
    __syncthreads();
  }
  if (i < n) excl[i] = tmp[t] - v;
  if (t == 1023) bsum[blockIdx.x] = tmp[1023];
}
// parallel exclusive scan of block sums (nb <= 64)
__global__ __launch_bounds__(64) void scan_bsum_k(int* __restrict__ bsum, int nb) {
  int l = threadIdx.x;
  int orig = (l < nb) ? bsum[l] : 0;
  int v = orig;
  for (int off = 1; off < 64; off <<= 1) {
    int u = __shfl_up(v, off);
    if (l >= off) v += u;
  }
  if (l < nb) bsum[l] = v - orig;
}
__global__ __launch_bounds__(256) void finalize_rowptr_k(const int* __restrict__ excl, const int* __restrict__ bsum,
                                                         int* __restrict__ rowp, int n, int e) {
  int i = blockIdx.x * 256 + threadIdx.x;
  if (i < n) rowp[i] = excl[i] + bsum[i >> 10];
  if (i == 0) rowp[n] = e;
}
__global__ __launch_bounds__(256) void scatter_k(const int* __restrict__ src, const int* __restrict__ dst,
                                                 const int* __restrict__ rowp, int* __restrict__ cur,
                                                 int* __restrict__ srt, int e) {
  int i = blockIdx.x * 256 + threadIdx.x;
  if (i < e) {
    int d = dst[i];
    int pos = rowp[d] + atomicAdd(&cur[d], 1);
    srt[pos] = src[i];
  }
}

// ---------------- weight / bias packing ----------------
__global__ __launch_bounds__(64) void pack_weights(const float* __restrict__ Wq, const float* __restrict__ Wk,
                                                   const float* __restrict__ Wv, const float* __restrict__ Ws,
                                                   const float* __restrict__ w0, ushort_t* __restrict__ wp_all,
                                                   ushort_t* __restrict__ wp_lin0) {
  int b = blockIdx.x, lane = threadIdx.x;
  if (b < 312) {
    int l = b / 104, t = b % 104;
    int ntg = t >> 1, kt = t & 1;
    int col = ntg * 16 + (lane & 15);
    int kb = kt * 32 + (lane >> 4) * 8;
    const float* W;
    int c, stride;
    if (col < 256)      { W = Wq + (long long)l * 64 * 256; c = col;       stride = 256; }
    else if (col < 512) { W = Wk + (long long)l * 64 * 256; c = col - 256; stride = 256; }
    else if (col < 768) { W = Wv + (long long)l * 64 * 256; c = col - 512; stride = 256; }
    else                { W = Ws + (long long)l * 64 * 64;  c = col - 768; stride = 64; }
    ushort_t vals[8];
#pragma unroll
    for (int e = 0; e < 8; e++) vals[e] = f2bf(W[(long long)(kb + e) * stride + c]);
    ushort_t* p = wp_all + (long long)l * (104 * 512) + ((long long)t * 64 + lane) * 8;
    ushort4 lo{vals[0], vals[1], vals[2], vals[3]}, hi{vals[4], vals[5], vals[6], vals[7]};
    *(ushort4*)p = lo;
    *(ushort4*)(p + 4) = hi;
  } else {
    int t = b - 312;  // 0..15: ntg=t>>2, kt=t&3
    int col = (t >> 2) * 16 + (lane & 15);
    int kb = (t & 3) * 32 + (lane >> 4) * 8;
    ushort_t vals[8];
#pragma unroll
    for (int e = 0; e < 8; e++) vals[e] = f2bf(w0[(long long)(kb + e) * 64 + col]);
    ushort_t* p = wp_lin0 + ((long long)t * 64 + lane) * 8;
    ushort4 lo{vals[0], vals[1], vals[2], vals[3]}, hi{vals[4], vals[5], vals[6], vals[7]};
    *(ushort4*)p = lo;
    *(ushort4*)(p + 4) = hi;
  }
}
__global__ __launch_bounds__(832) void pack_bias_k(const float* __restrict__ bq, const float* __restrict__ bk,
                                                   const float* __restrict__ bv, const float* __restrict__ bs,
                                                   float* __restrict__ bp) {
  int l = blockIdx.x, c = threadIdx.x;
  float v = (c < 256) ? bq[l * 256 + c]
          : (c < 512) ? bk[l * 256 + c - 256]
          : (c < 768) ? bv[l * 256 + c - 512]
          : bs[l * 64 + c - 768];
  bp[l * QSW + c] = v;
}

// ---------------- MFMA GEMM: C[n,outw](bf16) = A[n,K] @ W + bias ----------------
// 4 waves/block, each wave 64 rows x 64 cols (4x4 MFMA tile; W frags reused 4x).
template <int K, int AF32>
__global__ __launch_bounds__(256) void gemm_mfma(const void* __restrict__ Av, const ushort_t* __restrict__ Wp,
                                                 const float* __restrict__ bias, ushort_t* __restrict__ C,
                                                 int n, int outw) {
  constexpr int KT = K / 32;
  int lane = threadIdx.x & 63;
  int wv = __builtin_amdgcn_readfirstlane((int)(threadIdx.x >> 6));
  int m0 = (blockIdx.x * 4 + wv) * 64;
  int n0 = blockIdx.y * 64;
  int lr = lane & 15, lq = lane >> 4;

  bf16x8 a[4][KT];
#pragma unroll
  for (int mr = 0; mr < 4; mr++) {
    int row = m0 + mr * 16 + lr;
    if (row >= n) row = n - 1;
    if constexpr (AF32) {
      const float* Af = (const float*)Av;
#pragma unroll
      for (int kt = 0; kt < KT; kt++) {
        const float* p = Af + (long long)row * K + kt * 32 + lq * 8;
        float4 f0 = *(const float4*)p;
        float4 f1 = *(const float4*)(p + 4);
        u16x8 u;
        u[0] = f2bf(f0.x); u[1] = f2bf(f0.y); u[2] = f2bf(f0.z); u[3] = f2bf(f0.w);
        u[4] = f2bf(f1.x); u[5] = f2bf(f1.y); u[6] = f2bf(f1.z); u[7] = f2bf(f1.w);
        a[mr][kt] = __builtin_bit_cast(bf16x8, u);
      }
    } else {
      const ushort_t* Ab = (const ushort_t*)Av;
#pragma unroll
      for (int kt = 0; kt < KT; kt++)
        a[mr][kt] = *(const bf16x8*)(Ab + (long long)row * K + kt * 32 + lq * 8);
    }
  }
  f32x4 acc[4][4];
#pragma unroll
  for (int nt = 0; nt < 4; nt++) {
    float b = bias[n0 + nt * 16 + lr];
    f32x4 b4 = {b, b, b, b};
#pragma unroll
    for (int mr = 0; mr < 4; mr++) acc[mr][nt] = b4;
  }
#pragma unroll
  for (int nt = 0; nt < 4; nt++) {
    int ntg = (n0 >> 4) + nt;
    bf16x8 bw[KT];
#pragma unroll
    for (int kt = 0; kt < KT; kt++)
      bw[kt] = *(const bf16x8*)(Wp + ((long long)(ntg * KT + kt) * 64 + lane) * 8);
#pragma unroll
    for (int kt = 0; kt < KT; kt++)
#pragma unroll
      for (int mr = 0; mr < 4; mr++)
        acc[mr][nt] = __builtin_amdgcn_mfma_f32_16x16x32_bf16(a[mr][kt], bw[kt], acc[mr][nt], 0, 0, 0);
  }
#pragma unroll
  for (int mr = 0; mr < 4; mr++)
#pragma unroll
    for (int nt = 0; nt < 4; nt++)
#pragma unroll
      for (int r = 0; r < 4; r++) {
        int row = m0 + mr * 16 + lq * 4 + r;
        if (row < n) C[(long long)row * outw + n0 + nt * 16 + lr] = f2bf(acc[mr][nt][r]);
      }
}

// ---------------- fused attention + head-mean + skip + relu ----------------
// One wave/node. lane = half*32 + sl; sl covers 256 ch (4 heads x 8 lanes x 8 ch).
// Per iteration: 8 edges (4 per half), defer-max online softmax.
__global__ __launch_bounds__(256) void attn_k(const ushort_t* __restrict__ qs,
                                              const int* __restrict__ rowp, const int* __restrict__ srt,
                                              ushort_t* __restrict__ hn, int n) {
  int wvv = __builtin_amdgcn_readfirstlane((int)(threadIdx.x >> 6));
  int node = blockIdx.x * 4 + wvv;
  if (node >= n) return;
  int lane = threadIdx.x & 63;
  int half = lane >> 5;
  int sl = lane & 31;
  const uint4 qu = *(const uint4*)(qs + (long long)node * QSW + sl * 8);
  float qf[8];
  qf[0] = blo(qu.x); qf[1] = bhi(qu.x); qf[2] = blo(qu.y); qf[3] = bhi(qu.y);
  qf[4] = blo(qu.z); qf[5] = bhi(qu.z); qf[6] = blo(qu.w); qf[7] = bhi(qu.w);
  int rs = rowp[node], re = rowp[node + 1];
  int last = re - 1;
  float m = -INFINITY, d = 0.f;
  float a[8];
#pragma unroll
  for (int j = 0; j < 8; j++) a[j] = 0.f;

  for (int i = rs; i < re; i += 8) {
    int b0 = i + half * 4;
    int j0 = min(b0, last), j1 = min(b0 + 1, last), j2 = min(b0 + 2, last), j3 = min(b0 + 3, last);
    int i0 = srt[j0], i1 = srt[j1], i2 = srt[j2], i3 = srt[j3];
    const ushort_t* p0 = qs + (long long)i0 * QSW + 256 + sl * 8;
    const ushort_t* p1 = qs + (long long)i1 * QSW + 256 + sl * 8;
    const ushort_t* p2 = qs + (long long)i2 * QSW + 256 + sl * 8;
    const ushort_t* p3 = qs + (long long)i3 * QSW + 256 + sl * 8;
    uint4 k0 = *(const uint4*)p0;
    uint4 k1 = *(const uint4*)p1;
    uint4 k2 = *(const uint4*)p2;
    uint4 k3 = *(const uint4*)p3;
    uint4 v0 = *(const uint4*)(p0 + 256);
    uint4 v1 = *(const uint4*)(p1 + 256);
    uint4 v2 = *(const uint4*)(p2 + 256);
    uint4 v3 = *(const uint4*)(p3 + 256);
    float t0 = 0.f, t1 = 0.f, t2 = 0.f, t3 = 0.f;
    t0 = fmaf(qf[0], blo(k0.x), t0); t0 = fmaf(qf[1], bhi(k0.x), t0);
    t0 = fmaf(qf[2], blo(k0.y), t0); t0 = fmaf(qf[3], bhi(k0.y), t0);
    t0 = fmaf(qf[4], blo(k0.z), t0); t0 = fmaf(qf[5], bhi(k0.z), t0);
    t0 = fmaf(qf[6], blo(k0.w), t0); t0 = fmaf(qf[7], bhi(k0.w), t0);
    t1 = fmaf(qf[0], blo(k1.x), t1); t1 = fmaf(qf[1], bhi(k1.x), t1);
    t1 = fmaf(qf[2], blo(k1.y), t1); t1 = fmaf(qf[3], bhi(k1.y), t1);
    t1 = fmaf(qf[4], blo(k1.z), t1); t1 = fmaf(qf[5], bhi(k1.z), t1);
    t1 = fmaf(qf[6], blo(k1.w), t1); t1 = fmaf(qf[7], bhi(k1.w), t1);
    t2 = fmaf(qf[0], blo(k2.x), t2); t2 = fmaf(qf[1], bhi(k2.x), t2);
    t2 = fmaf(qf[2], blo(k2.y), t2); t2 = fmaf(qf[3], bhi(k2.y), t2);
    t2 = fmaf(qf[4], blo(k2.z), t2); t2 = fmaf(qf[5], bhi(k2.z), t2);
    t2 = fmaf(qf[6], blo(k2.w), t2); t2 = fmaf(qf[7], bhi(k2.w), t2);
    t3 = fmaf(qf[0], blo(k3.x), t3); t3 = fmaf(qf[1], bhi(k3.x), t3);
    t3 = fmaf(qf[2], blo(k3.y), t3); t3 = fmaf(qf[3], bhi(k3.y), t3);
    t3 = fmaf(qf[4], blo(k3.z), t3); t3 = fmaf(qf[5], bhi(k3.z), t3);
    t3 = fmaf(qf[6], blo(k3.w), t3); t3 = fmaf(qf[7], bhi(k3.w), t3);
    t0 += __shfl_xor(t0, 1); t1 += __shfl_xor(t1, 1); t2 += __shfl_xor(t2, 1); t3 += __shfl_xor(t3, 1);
    t0 += __shfl_xor(t0, 2); t1 += __shfl_xor(t1, 2); t2 += __shfl_xor(t2, 2); t3 += __shfl_xor(t3, 2);
    t0 += __shfl_xor(t0, 4); t1 += __shfl_xor(t1, 4); t2 += __shfl_xor(t2, 4); t3 += __shfl_xor(t3, 4);
    t0 *= 0.125f; t1 *= 0.125f; t2 *= 0.125f; t3 *= 0.125f;  // 1/sqrt(64)
    if (b0 > last) t0 = -INFINITY;
    if (b0 + 1 > last) t1 = -INFINITY;
    if (b0 + 2 > last) t2 = -INFINITY;
    if (b0 + 3 > last) t3 = -INFINITY;
    float lm = fmaxf(fmaxf(t0, t1), fmaxf(t2, t3));
    lm = fmaxf(lm, __shfl_xor(lm, 32));
    if (__any(lm > m + 8.f)) {  // defer-max: rescale only on significant growth
      float mn = fmaxf(m, lm);
      float co = __expf(m - mn);  // first iter: exp(-inf)=0
      d *= co;
#pragma unroll
      for (int j = 0; j < 8; j++) a[j] *= co;
      m = mn;
    }
    float p0e = __expf(t0 - m), p1e = __expf(t1 - m), p2e = __expf(t2 - m), p3e = __expf(t3 - m);
    d += (p0e + p1e) + (p2e + p3e);
    a[0] += p0e * blo(v0.x) + p1e * blo(v1.x) + p2e * blo(v2.x) + p3e * blo(v3.x);
    a[1] += p0e * bhi(v0.x) + p1e * bhi(v1.x) + p2e * bhi(v2.x) + p3e * bhi(v3.x);
    a[2] += p0e * blo(v0.y) + p1e * blo(v1.y) + p2e * blo(v2.y) + p3e * blo(v3.y);
    a[3] += p0e * bhi(v0.y) + p1e * bhi(v1.y) + p2e * bhi(v2.y) + p3e * bhi(v3.y);
    a[4] += p0e * blo(v0.z) + p1e * blo(v1.z) + p2e * blo(v2.z) + p3e * blo(v3.z);
    a[5] += p0e * bhi(v0.z) + p1e * bhi(v1.z) + p2e * bhi(v2.z) + p3e * bhi(v3.z);
    a[6] += p0e * blo(v0.w) + p1e * blo(v1.w) + p2e * blo(v2.w) + p3e * blo(v3.w);
    a[7] += p0e * bhi(v0.w) + p1e * bhi(v1.w) + p2e * bhi(v2.w) + p3e * bhi(v3.w);
  }
  // merge halves (same head at lane^32)
  d += __shfl_xor(d, 32);
#pragma unroll
  for (int j = 0; j < 8; j++) a[j] += __shfl_xor(a[j], 32);
  float inv = (d > 0.f) ? 1.f / d : 0.f;
  float r[8];
#pragma unroll
  for (int j = 0; j < 8; j++) {
    r[j] = a[j] * inv;
    r[j] += __shfl_xor(r[j], 8);   // head ^1
    r[j] += __shfl_xor(r[j], 16);  // head ^2
  }
  if (lane < 8) {
    const u16x8 s8 = *(const u16x8*)(qs + (long long)node * QSW + 768 + lane * 8);
    u16x8 o;
#pragma unroll
    for (int j = 0; j < 8; j++)
      o[j] = f2bf(fmaxf(r[j] * 0.25f + bf2f(s8[j]), 0.f));
    *(u16x8*)(hn + (long long)node * HID + lane * 8) = o;
  }
}

// ---------------- global add pool (run-length; batch is sorted) ----------------
#define POOL_NPB 128
__global__ __launch_bounds__(64) void pool_k(const ushort_t* __restrict__ h, const int* __restrict__ batch,
                                             float* __restrict__ out, int n) {
  int c = threadIdx.x;
  int n0 = blockIdx.x * POOL_NPB;
  int n1 = n0 + POOL_NPB;
  if (n1 > n) n1 = n;
  if (n0 >= n) return;
  float acc = 0.f;
  int g = batch[n0];
  for (int node = n0; node < n1; node++) {
    int gb = batch[node];
    if (gb != g) {
      atomicAdd(&out[g * 64 + c], acc);
      acc = 0.f;
      g = gb;
    }
    acc += bf2f(h[(long long)node * 64 + c]);
  }
  atomicAdd(&out[g * 64 + c], acc);
}

extern "C" void kernel_launch(void* const* d_in, const int* in_sizes, int n_in,
                              void* d_out, int out_size, void* d_ws, size_t ws_size,
                              hipStream_t stream) {
  const float* x  = (const float*)d_in[0];
  const int* ei   = (const int*)d_in[1];
  const int* batch = (const int*)d_in[2];
  const float* w0 = (const float*)d_in[3];
  const float* b0 = (const float*)d_in[4];
  const float* Wq = (const float*)d_in[5];
  const float* bq = (const float*)d_in[6];
  const float* Wk = (const float*)d_in[7];
  const float* bk = (const float*)d_in[8];
  const float* Wv = (const float*)d_in[9];
  const float* bv = (const float*)d_in[10];
  const float* Ws = (const float*)d_in[11];
  const float* bs = (const float*)d_in[12];
  int N = in_sizes[0] / F_IN;
  int E = in_sizes[1] / 2;
  const int* esrc = ei;
  const int* edst = ei + E;

  // ---- workspace layout ----
  float* bp = (float*)d_ws;                               // 3*832 f32
  ushort_t* h0   = (ushort_t*)(bp + 3 * QSW);
  ushort_t* h1   = h0 + (long long)N * HID;
  ushort_t* qsb  = h1 + (long long)N * HID;               // N x 832
  ushort_t* wp_all  = qsb + (long long)N * QSW;           // 3 * 104 * 512
  ushort_t* wp_lin0 = wp_all + 3 * 104 * 512;             // 16 * 512
  int* cnt  = (int*)(wp_lin0 + 16 * 512);
  int* cur  = cnt + N;
  int* excl = cur + N;
  int* rowp = excl + N;
  int* bsum = rowp + N + 1;
  int* srt  = bsum + 64;

  int nbN = (N + 255) / 256;
  int nbE = (E + 255) / 256;
  int sbBlocks = (N + 1023) / 1024;

  // CSR by dst
  hipMemsetAsync(cnt, 0, (size_t)2 * N * sizeof(int), stream);  // cnt + cur contiguous
  hist_k<<<nbE, 256, 0, stream>>>(edst, cnt, E);
  scan_block_k<<<sbBlocks, 1024, 0, stream>>>(cnt, excl, bsum, N);
  scan_bsum_k<<<1, 64, 0, stream>>>(bsum, sbBlocks);
  finalize_rowptr_k<<<nbN, 256, 0, stream>>>(excl, bsum, rowp, N, E);
  scatter_k<<<nbE, 256, 0, stream>>>(esrc, edst, rowp, cur, srt, E);

  // weight/bias packing
  pack_weights<<<328, 64, 0, stream>>>(Wq, Wk, Wv, Ws, w0, wp_all, wp_lin0);
  pack_bias_k<<<3, 832, 0, stream>>>(bq, bk, bv, bs, bp);

  int mBlocks = (N + 255) / 256;

  // h0 = x @ lin0_w + lin0_b  (A fp32 direct)
  gemm_mfma<128, 1><<<dim3(mBlocks, 1), 256, 0, stream>>>(x, wp_lin0, b0, h0, N, HID);

  ushort_t* hc = h0;
  ushort_t* hx = h1;
  for (int l = 0; l < NLAYER; l++) {
    gemm_mfma<64, 0><<<dim3(mBlocks, 13), 256, 0, stream>>>(hc, wp_all + (long long)l * 104 * 512,
                                                            bp + l * QSW, qsb, N, QSW);
    attn_k<<<(N + 3) / 4, 256, 0, stream>>>(qsb, rowp, srt, hx, N);
    ushort_t* t = hc; hc = hx; hx = t;
  }

  hipMemsetAsync(d_out, 0, (size_t)out_size * sizeof(float), stream);
  pool_k<<<(N + POOL_NPB - 1) / POOL_NPB, 64, 0, stream>>>(hc, batch, (float*)d_out, N);
}